// Round 5
// baseline (40.788 us; speedup 1.0000x reference)
//
#include <hip/hip_runtime.h>
#include <hip/hip_bf16.h>
#include <math.h>

#define COUPLING 0.12f
#define EPSV 1e-8f
#define SCALE2L2E 2.8853900817779268f   // 2*log2(e): folds tanh's 2x and exp->exp2

typedef __attribute__((ext_vector_type(8))) short bf16x8;
typedef __attribute__((ext_vector_type(4))) float f32x4;

// tanh(x) from y = 2x*log2(e):  tanh = 1 - 2/(1+2^y). Inf-safe both ways.
__device__ __forceinline__ float tanh_from_e2(float y) {
    float e = __builtin_amdgcn_exp2f(y);
    float r = __builtin_amdgcn_rcpf(1.0f + e);
    return fmaf(-2.0f, r, 1.0f);
}
__device__ __forceinline__ float tanh_fast(float x) {
    return tanh_from_e2(SCALE2L2E * x);
}
// sigma(y) = 1/(1+2^y); tanh = 1 - 2*sigma. Accumulate sigma, fix up with
// valid-row count N at reduction: sum(tanh) = N - 2*sum(sigma).
__device__ __forceinline__ float sig_e2(float y) {
    float e = __builtin_amdgcn_exp2f(y);
    return __builtin_amdgcn_rcpf(1.0f + e);
}

__device__ __forceinline__ short f2bf(float f) {
    __hip_bfloat16 h = __float2bfloat16(f);
    return __builtin_bit_cast(short, h);
}

// Pre-pass (1 block, 128 threads).
__global__ __launch_bounds__(128) void phot_prep(
    const float* __restrict__ heads_w, const float* __restrict__ heads_b,
    const float* __restrict__ cand, float* __restrict__ cpre,
    short* __restrict__ wbf)
{
    const int oh = threadIdx.x;               // 0..127
    const float* wr = heads_w + (size_t)oh * 64;
    float s0 = heads_b[oh], s1 = 0.f, s2 = 0.f, s3 = 0.f;
    #pragma unroll
    for (int k = 0; k < 32; k += 4) {
        s0 = fmaf(wr[k+0], cand[k+0], s0);
        s1 = fmaf(wr[k+1], cand[k+1], s1);
        s2 = fmaf(wr[k+2], cand[k+2], s2);
        s3 = fmaf(wr[k+3], cand[k+3], s3);
    }
    cpre[oh] = SCALE2L2E * ((s0 + s1) + (s2 + s3));
    short* wo = wbf + (size_t)oh * 32;
    #pragma unroll
    for (int k = 0; k < 32; ++k) wo[k] = f2bf(SCALE2L2E * wr[32 + k]);
}

// Main, round-8: depth-3 phased pipeline, residency-guaranteed config.
// R4 post-mortem: RAW barriers alone were ~neutral (main ~30us). Remaining
// suspects: (a) in-flight depth too shallow (8KB/block), (b) fragile
// 8-blocks/CU residency assumption (if VGPR>64, grid 2048 runs as 1.5
// sequential passes). This round removes both:
//  - nblk=1024, launch_bounds(256,4): 4 blocks/CU resident for ANY VGPR<=128,
//    zero spill risk. K=32 tiles/block, PH=8 phases of 4 tiles.
//  - Ring-4 LDS (4 x 4 x 1KB bf16), prefetch issued 3 PHASES ahead into
//    three NAMED pre-register sets (static indexing only; runtime-indexed
//    vectors go to scratch). Phase loop unrolled x3 so set/slot indices are
//    compile-time. In-flight: 24KB/block x 1024 blocks ~ 24MB >> 5.7MB
//    needed to saturate 6.3TB/s at ~900cy latency.
//  - Per phase: SLOADP(q+3) first (issue early), SWRITEP(q+1) (counted
//    vmcnt wait on loads issued 2 phases ago), 4x CTILE(q) from LDS,
//    then lgkmcnt(0) + raw s_barrier (vmem stays in flight across it).
// C/D layout: col=lane&15, row=(lane>>4)*4+reg (m89-verified).
// Swizzle (verified absmax=0 in R3/R4): chunk' = chunk ^ (row&3), 16B granule.
__global__ __launch_bounds__(256, 4) void phot_main(
    const float* __restrict__ z_past,   // [P][32] fp32
    const short* __restrict__ wbf,      // [128][32] bf16, pre-scaled
    const float* __restrict__ cpre_g,   // [128] f32, pre-scaled
    float* __restrict__ partials,       // [NB][128]
    int P, int NB)                      // NB = grid size
{
    __shared__ float wacc[128];
    __shared__ __align__(16) unsigned short zb[4][4][512];  // [slot][tile][16x32 bf16]

    const int tid  = threadIdx.x;
    const int lane = tid & 63;
    const int wv   = tid >> 6;
    const int col  = lane & 15;   // A-row / B-col / C-col
    const int kg   = lane >> 4;   // k-group (k = kg*8 + e)

    // This wave's 2 channel groups.
    const int g0 = wv * 2, g1 = g0 + 1;
    const bf16x8 bfA = *(const bf16x8*)(wbf + (size_t)(g0 * 16 + col) * 32 + kg * 8);
    const bf16x8 bfB = *(const bf16x8*)(wbf + (size_t)(g1 * 16 + col) * 32 + kg * 8);
    const float  cpA = cpre_g[g0 * 16 + col];
    const float  cpB = cpre_g[g1 * 16 + col];

    f32x4 accA = {0,0,0,0}, accB = {0,0,0,0};

    const int T  = (P + 15) >> 4;             // total 16-row tiles
    const int Tf = P >> 4;                    // full tiles
    const int b  = blockIdx.x;
    const int K  = (b < T) ? ((T - 1 - b) / NB + 1) : 0;   // tiles for this block
    const int PH = (K + 3) >> 2;              // phases of 4 tiles

    // Stager lane mapping: lane covers tile floats [sr*32 + sc*8, +8).
    const int sr = lane >> 2;                 // row 0..15
    const int sc = lane & 3;                  // chunk 0..3 (8 floats = 16B bf16)
    const int woff = sr * 32 + ((sc ^ (sr & 3)) << 3);   // ushort offset in tile

    // Reader offset: row=col, chunk=kg, same XOR swizzle.
    const int roff = col * 32 + ((kg ^ (col & 3)) << 3); // ushort offset in tile

    // Three named prefetch register sets (depth-3; static indexing only).
    f32x4 preA0 = {0,0,0,0}, preB0 = {0,0,0,0};
    f32x4 preA1 = {0,0,0,0}, preB1 = {0,0,0,0};
    f32x4 preA2 = {0,0,0,0}, preB2 = {0,0,0,0};

    // Issue this wave's tile loads for phase ph into pre set S.
    #define SLOADP(ph, S) { \
        const int j_ = 4 * (ph) + wv; \
        if (j_ < K) { \
            const int tt_ = b + j_ * NB; \
            int grow = tt_ * 16 + sr; if (grow > P - 1) grow = P - 1; \
            const float* g_ = z_past + (size_t)grow * 32 + sc * 8; \
            preA##S = *(const f32x4*)g_; \
            preB##S = *(const f32x4*)(g_ + 4); \
        } }
    // Convert + publish pre set S into ring slot (ph)&3.
    #define SWRITEP(ph, S) { \
        const int j_ = 4 * (ph) + wv; \
        if (j_ < K) { \
            bf16x8 w_; \
            w_[0]=f2bf(preA##S[0]); w_[1]=f2bf(preA##S[1]); \
            w_[2]=f2bf(preA##S[2]); w_[3]=f2bf(preA##S[3]); \
            w_[4]=f2bf(preB##S[0]); w_[5]=f2bf(preB##S[1]); \
            w_[6]=f2bf(preB##S[2]); w_[7]=f2bf(preB##S[3]); \
            *(bf16x8*)(&zb[(ph) & 3][wv][woff]) = w_; \
        } }
    // Compute tile j of phase p from ring slot p&3.
    #define CTILE(p, j) { \
        const int jj_ = 4 * (p) + (j); \
        if (jj_ < K) { \
            const int tt_ = b + jj_ * NB; \
            const bf16x8 a_ = *(const bf16x8*)(&zb[(p) & 3][j][roff]); \
            const int base_ = tt_ * 16; \
            if (base_ + 16 <= P) { \
                f32x4 c_ = {cpA, cpA, cpA, cpA}; \
                f32x4 d_ = __builtin_amdgcn_mfma_f32_16x16x32_bf16(a_, bfA, c_, 0, 0, 0); \
                accA[0] += sig_e2(d_[0]); accA[1] += sig_e2(d_[1]); \
                accA[2] += sig_e2(d_[2]); accA[3] += sig_e2(d_[3]); \
                c_ = {cpB, cpB, cpB, cpB}; \
                d_ = __builtin_amdgcn_mfma_f32_16x16x32_bf16(a_, bfB, c_, 0, 0, 0); \
                accB[0] += sig_e2(d_[0]); accB[1] += sig_e2(d_[1]); \
                accB[2] += sig_e2(d_[2]); accB[3] += sig_e2(d_[3]); \
            } else { \
                const int r0_ = base_ + kg * 4; \
                f32x4 c_ = {cpA, cpA, cpA, cpA}; \
                f32x4 d_ = __builtin_amdgcn_mfma_f32_16x16x32_bf16(a_, bfA, c_, 0, 0, 0); \
                if (r0_ + 0 < P) accA[0] += sig_e2(d_[0]); \
                if (r0_ + 1 < P) accA[1] += sig_e2(d_[1]); \
                if (r0_ + 2 < P) accA[2] += sig_e2(d_[2]); \
                if (r0_ + 3 < P) accA[3] += sig_e2(d_[3]); \
                c_ = {cpB, cpB, cpB, cpB}; \
                d_ = __builtin_amdgcn_mfma_f32_16x16x32_bf16(a_, bfB, c_, 0, 0, 0); \
                if (r0_ + 0 < P) accB[0] += sig_e2(d_[0]); \
                if (r0_ + 1 < P) accB[1] += sig_e2(d_[1]); \
                if (r0_ + 2 < P) accB[2] += sig_e2(d_[2]); \
                if (r0_ + 3 < P) accB[3] += sig_e2(d_[3]); \
            } \
        } }

    #define SYNC { asm volatile("s_waitcnt lgkmcnt(0)" ::: "memory"); \
                   __builtin_amdgcn_s_barrier(); }

    if (K > 0) {
        // Prologue: load phases 0,1,2; publish phase 0 (counted vmcnt wait).
        SLOADP(0, 0) SLOADP(1, 1) SLOADP(2, 2)
        SWRITEP(0, 0)
        SYNC

        // Steady state, unrolled x3 so pre-set/slot indices stay static.
        // Phase q: SLOADP(q+3 -> set q%3), SWRITEP(q+1 <- set (q+1)%3),
        // compute phase q from slot q&3, sync.
        for (int p = 0; p < PH; p += 3) {
            {
                SLOADP(p + 3, 0) SWRITEP(p + 1, 1)
                CTILE(p, 0) CTILE(p, 1) CTILE(p, 2) CTILE(p, 3)
                SYNC
            }
            if (p + 1 < PH) {
                SLOADP(p + 4, 1) SWRITEP(p + 2, 2)
                CTILE(p + 1, 0) CTILE(p + 1, 1) CTILE(p + 1, 2) CTILE(p + 1, 3)
                SYNC
            }
            if (p + 2 < PH) {
                SLOADP(p + 5, 2) SWRITEP(p + 3, 0)
                CTILE(p + 2, 0) CTILE(p + 2, 1) CTILE(p + 2, 2) CTILE(p + 2, 3)
                SYNC
            }
        }
    }
    #undef SLOADP
    #undef SWRITEP
    #undef CTILE
    #undef SYNC

    // Per-lane valid-row count (analytic).
    float nsum = 0.0f;
    if (K > 0) {
        int nfull = (b < Tf) ? ((Tf - 1 - b) / NB + 1) : 0;
        nsum = 4.0f * (float)nfull;
        if (Tf < T && b <= Tf && ((Tf - b) % NB) == 0) {   // block owns partial tile
            int prem = P - Tf * 16;
            int nv = prem - kg * 4; if (nv < 0) nv = 0; if (nv > 4) nv = 4;
            nsum += (float)nv;
        }
    }

    // sum(tanh) = nsum - 2*sum(sigma); fold 4 row-regs, then 4 k-groups.
    float sA = nsum - 2.0f * ((accA[0] + accA[1]) + (accA[2] + accA[3]));
    sA += __shfl_xor(sA, 16, 64);
    sA += __shfl_xor(sA, 32, 64);
    float sB = nsum - 2.0f * ((accB[0] + accB[1]) + (accB[2] + accB[3]));
    sB += __shfl_xor(sB, 16, 64);
    sB += __shfl_xor(sB, 32, 64);
    if (lane < 16) {
        wacc[g0 * 16 + lane] = sA;
        wacc[g1 * 16 + lane] = sB;
    }
    __syncthreads();
    if (tid < 128) {
        partials[(size_t)b * 128 + tid] = wacc[tid];
    }
}

// Mid-reduce: 128 blocks fold partials[nblk][128] -> mid[128][128].
__global__ __launch_bounds__(128) void phot_mid(
    const float* __restrict__ partials, float* __restrict__ mid, int nblk)
{
    const int g = blockIdx.x, t = threadIdx.x;
    const int seg = nblk >> 7, rem = nblk & 127;
    const int b0  = g * seg + (g < rem ? g : rem);
    const int cnt = seg + (g < rem ? 1 : 0);
    const float* p0 = partials + (size_t)b0 * 128 + t;
    float s = 0.f;
    for (int i = 0; i < cnt; ++i) s += p0[(size_t)i * 128];
    mid[(size_t)g * 128 + t] = s;
}

// Finalize (validated rounds 1-4); fed by mid with nblk=128.
__global__ __launch_bounds__(1024) void phot_finalize(
    const float* __restrict__ partials, int nblk, int P,
    const float* __restrict__ out_w,      // [32][128]
    const float* __restrict__ out_b,      // [32]
    const float* __restrict__ rel_bias,   // [129][2]
    const float* __restrict__ cand,       // [32]
    const float* __restrict__ norm_scale, // [1]
    const int* __restrict__ posp,         // [1]
    float* __restrict__ out)              // [32]
{
    __shared__ float  sh[1024];
    __shared__ float  cm[128];
    __shared__ float  outv[32];
    __shared__ double db[512];
    __shared__ float  bm[2];

    const int t  = threadIdx.x;
    const int oh = t & 127;
    const int sl = t >> 7;          // 0..7 slices over blocks

    const int seg = nblk >> 3;      // nblk is a multiple of 8
    const int b0  = sl * seg;
    float a0=0.f,a1=0.f,a2=0.f,a3=0.f,a4=0.f,a5=0.f,a6=0.f,a7=0.f;
    int i = 0;
    for (; i + 8 <= seg; i += 8) {
        const float* pp = partials + (size_t)(b0 + i) * 128 + oh;
        a0 += pp[0*128]; a1 += pp[1*128]; a2 += pp[2*128]; a3 += pp[3*128];
        a4 += pp[4*128]; a5 += pp[5*128]; a6 += pp[6*128]; a7 += pp[7*128];
    }
    for (; i < seg; ++i) a0 += partials[(size_t)(b0 + i) * 128 + oh];
    sh[t] = ((a0+a1)+(a2+a3)) + ((a4+a5)+(a6+a7));
    __syncthreads();

    if (t < 128) {
        float s = 0.0f;
        #pragma unroll
        for (int s2 = 0; s2 < 8; ++s2) s += sh[t + 128*s2];
        cm[t] = s / (float)P;
    }

    // rel-bias mean, closed form per bin; idx(p)=clamp(a+p,0,128), a=pos-P+64
    if (t < 512) {
        const int c = t >> 8, j = t & 255;
        double v = 0.0;
        if (j <= 128) {
            const long long pos = (long long)(*posp);
            const long long a = pos - (long long)P + 64;
            double cnt;
            if (j == 0) {
                long long hi = -a; if (hi > (long long)P - 1) hi = (long long)P - 1;
                cnt = (hi >= 0) ? (double)(hi + 1) : 0.0;
            } else if (j == 128) {
                long long lo = 128 - a; if (lo < 0) lo = 0;
                cnt = (lo <= (long long)P - 1) ? (double)((long long)P - lo) : 0.0;
            } else {
                long long p = (long long)j - a;
                cnt = (p >= 0 && p < (long long)P) ? 1.0 : 0.0;
            }
            v = cnt * (double)rel_bias[2*j + c];
        }
        db[t] = v;
    }
    __syncthreads();
    #pragma unroll
    for (int s = 128; s >= 1; s >>= 1) {
        if (t < 512 && (t & 255) < s) db[t] += db[t + s];
        __syncthreads();
    }
    if (t < 2) bm[t] = (float)(db[t << 8] / (double)P);
    __syncthreads();

    if (t < 32) {
        const float* wr = out_w + t * 128;
        float o0 = out_b[t], o1 = 0.f, o2 = 0.f, o3 = 0.f;
        #pragma unroll
        for (int j = 0; j < 128; j += 4) {
            o0 = fmaf(wr[j+0], cm[j+0], o0);
            o1 = fmaf(wr[j+1], cm[j+1], o1);
            o2 = fmaf(wr[j+2], cm[j+2], o2);
            o3 = fmaf(wr[j+3], cm[j+3], o3);
        }
        outv[t] = (o0+o1) + (o2+o3);
    }
    __syncthreads();

    if (t < 32) {
        float zt = tanh_fast(cand[t] + COUPLING * (outv[t] + bm[t & 1]));
        float other = __shfl_xor(zt, 1, 64);
        float m = fmaf(zt, zt, other * other);
        #pragma unroll
        for (int off = 2; off < 32; off <<= 1) m = fmaxf(m, __shfl_xor(m, off, 64));
        float scale = norm_scale[0] / sqrtf(m + EPSV);
        out[t] = (m > 0.0f) ? zt * scale : zt;
    }
}

extern "C" void kernel_launch(void* const* d_in, const int* in_sizes, int n_in,
                              void* d_out, int out_size, void* d_ws, size_t ws_size,
                              hipStream_t stream)
{
    const float* cand       = (const float*)d_in[0];
    const float* z_past     = (const float*)d_in[1];
    const float* heads_w    = (const float*)d_in[2];
    const float* heads_b    = (const float*)d_in[3];
    const float* out_w      = (const float*)d_in[4];
    const float* out_b      = (const float*)d_in[5];
    const float* rel_bias   = (const float*)d_in[6];
    const float* norm_scale = (const float*)d_in[7];
    const int*   posp       = (const int*)d_in[8];

    const int P = in_sizes[1] / 32;

    int nblk = 1024;     // 4 blocks/CU, residency guaranteed for any VGPR<=128
    size_t need = ((size_t)nblk * 128 + 128 * 128 + 128) * sizeof(float)
                + 128 * 32 * sizeof(short);
    if (need > ws_size) {
        nblk = (int)((ws_size - (128 * 128 + 128) * sizeof(float)
                      - 128 * 32 * sizeof(short)) / (128 * sizeof(float)));
        nblk &= ~7;
        if (nblk < 8) nblk = 8;
    }
    float* partials = (float*)d_ws;
    float* mid      = partials + (size_t)nblk * 128;
    float* cpre     = mid + 128 * 128;
    short* wbf      = (short*)(cpre + 128);

    phot_prep<<<1, 128, 0, stream>>>(heads_w, heads_b, cand, cpre, wbf);
    phot_main<<<nblk, 256, 0, stream>>>(z_past, wbf, cpre, partials, P, nblk);
    phot_mid<<<128, 128, 0, stream>>>(partials, mid, nblk);
    phot_finalize<<<1, 1024, 0, stream>>>(mid, 128, P, out_w, out_b,
                                          rel_bias, cand, norm_scale, posp,
                                          (float*)d_out);
}

// Round 6
// 37.628 us; speedup vs baseline: 1.0840x; 1.0840x over previous
//
#include <hip/hip_runtime.h>
#include <hip/hip_bf16.h>
#include <math.h>

#define COUPLING 0.12f
#define EPSV 1e-8f
#define SCALE2L2E 2.8853900817779268f   // 2*log2(e): folds tanh's 2x and exp->exp2

typedef __attribute__((ext_vector_type(8))) short bf16x8;
typedef __attribute__((ext_vector_type(4))) float f32x4;

// tanh(x) from y = 2x*log2(e):  tanh = 1 - 2/(1+2^y). Inf-safe both ways.
__device__ __forceinline__ float tanh_from_e2(float y) {
    float e = __builtin_amdgcn_exp2f(y);
    float r = __builtin_amdgcn_rcpf(1.0f + e);
    return fmaf(-2.0f, r, 1.0f);
}
__device__ __forceinline__ float tanh_fast(float x) {
    return tanh_from_e2(SCALE2L2E * x);
}
// sigma(y) = 1/(1+2^y); tanh = 1 - 2*sigma. Accumulate sigma, fix up with
// valid-row count N at reduction: sum(tanh) = N - 2*sum(sigma).
__device__ __forceinline__ float sig_e2(float y) {
    float e = __builtin_amdgcn_exp2f(y);
    return __builtin_amdgcn_rcpf(1.0f + e);
}

__device__ __forceinline__ short f2bf(float f) {
    __hip_bfloat16 h = __float2bfloat16(f);
    return __builtin_bit_cast(short, h);
}

// Main, round-9: prep FUSED into main (4-launch chain was never attacked;
// every loop-side theory -- barriers R4, depth R5, occupancy R1/R2,
// registers R3 -- came back neutral. This round tests the accounting:
// 2 launches instead of 4, no wbf/cpre global round-trip, no phot_mid).
//  - Per-block prep phase: threads 0..127 compute wbf (bf16, pre-scaled)
//    and cpre into LDS (~1us amortized; heads_w is L2-resident).
//  - Loop body: UNCHANGED R4 structure (best measured, absmax 0): phases of
//    4 tiles, ring-3 LDS, single rolling pre-register set, raw s_barrier +
//    lgkmcnt(0) only (vmem stays in flight across barriers), chunk
//    XOR-swizzle on both ds_write and ds_read sides.
// C/D layout: col=lane&15, row=(lane>>4)*4+reg (m89-verified).
__global__ __launch_bounds__(256, 4) void phot_main(
    const float* __restrict__ z_past,   // [P][32] fp32
    const float* __restrict__ heads_w,  // [128][64]
    const float* __restrict__ heads_b,  // [128]
    const float* __restrict__ cand,     // [32]
    float* __restrict__ partials,       // [NB][128]
    int P, int NB)                      // NB = grid size
{
    __shared__ float wacc[128];
    __shared__ float cpre_l[128];
    __shared__ __align__(16) unsigned short wbf_l[128][32];   // 8KB bf16 weights
    __shared__ __align__(16) unsigned short zb[3][4][512];    // ring: [slot][tile][16x32]

    const int tid  = threadIdx.x;
    const int lane = tid & 63;
    const int wv   = tid >> 6;
    const int col  = lane & 15;   // A-row / B-col / C-col
    const int kg   = lane >> 4;   // k-group (k = kg*8 + e)

    // ---- prep phase (block-local; replaces the phot_prep kernel) ----
    if (tid < 128) {
        const float* wr = heads_w + (size_t)tid * 64;
        float s0 = heads_b[tid], s1 = 0.f, s2 = 0.f, s3 = 0.f;
        #pragma unroll
        for (int k = 0; k < 32; k += 4) {
            s0 = fmaf(wr[k+0], cand[k+0], s0);
            s1 = fmaf(wr[k+1], cand[k+1], s1);
            s2 = fmaf(wr[k+2], cand[k+2], s2);
            s3 = fmaf(wr[k+3], cand[k+3], s3);
        }
        cpre_l[tid] = SCALE2L2E * ((s0 + s1) + (s2 + s3));
        #pragma unroll
        for (int k = 0; k < 32; ++k)
            wbf_l[tid][k] = (unsigned short)f2bf(SCALE2L2E * wr[32 + k]);
    }
    __syncthreads();

    // This wave's 2 channel groups (B fragments from LDS).
    const int g0 = wv * 2, g1 = g0 + 1;
    const bf16x8 bfA = *(const bf16x8*)&wbf_l[g0 * 16 + col][kg * 8];
    const bf16x8 bfB = *(const bf16x8*)&wbf_l[g1 * 16 + col][kg * 8];
    const float  cpA = cpre_l[g0 * 16 + col];
    const float  cpB = cpre_l[g1 * 16 + col];

    f32x4 accA = {0,0,0,0}, accB = {0,0,0,0};

    const int T  = (P + 15) >> 4;             // total 16-row tiles
    const int Tf = P >> 4;                    // full tiles
    const int b  = blockIdx.x;
    const int K  = (b < T) ? ((T - 1 - b) / NB + 1) : 0;   // tiles for this block
    const int PH = (K + 3) >> 2;              // phases of 4 tiles

    // Stager lane mapping: lane covers tile floats [sr*32 + sc*8, +8).
    const int sr = lane >> 2;                 // row 0..15
    const int sc = lane & 3;                  // chunk 0..3 (8 floats = 16B bf16)
    const int woff = sr * 32 + ((sc ^ (sr & 3)) << 3);   // ushort offset in tile

    // Reader offset: row=col, chunk=kg, same XOR swizzle.
    const int roff = col * 32 + ((kg ^ (col & 3)) << 3); // ushort offset in tile

    f32x4 preA, preB;

    // Issue this wave's tile loads for phase ph into the rolling pre set.
    #define SLOADP(ph) { \
        const int j_ = 4 * (ph) + wv; \
        if (j_ < K) { \
            const int tt_ = b + j_ * NB; \
            int grow = tt_ * 16 + sr; if (grow > P - 1) grow = P - 1; \
            const float* g_ = z_past + (size_t)grow * 32 + sc * 8; \
            preA = *(const f32x4*)g_; \
            preB = *(const f32x4*)(g_ + 4); \
        } }
    // Convert + publish pre set into ring slot (ph)%3 (compiler inserts the
    // counted vmcnt for preA/preB -- the only outstanding vmem ops).
    #define SWRITEP(ph) { \
        const int j_ = 4 * (ph) + wv; \
        if (j_ < K) { \
            bf16x8 w_; \
            w_[0]=f2bf(preA[0]); w_[1]=f2bf(preA[1]); w_[2]=f2bf(preA[2]); w_[3]=f2bf(preA[3]); \
            w_[4]=f2bf(preB[0]); w_[5]=f2bf(preB[1]); w_[6]=f2bf(preB[2]); w_[7]=f2bf(preB[3]); \
            *(bf16x8*)(&zb[(ph) % 3][wv][woff]) = w_; \
        } }
    // Compute tile j of phase p from ring slot p%3.
    #define CTILE(p, j) { \
        const int jj_ = 4 * (p) + (j); \
        if (jj_ < K) { \
            const int tt_ = b + jj_ * NB; \
            const bf16x8 a_ = *(const bf16x8*)(&zb[(p) % 3][j][roff]); \
            const int base_ = tt_ * 16; \
            if (base_ + 16 <= P) { \
                f32x4 c_ = {cpA, cpA, cpA, cpA}; \
                f32x4 d_ = __builtin_amdgcn_mfma_f32_16x16x32_bf16(a_, bfA, c_, 0, 0, 0); \
                accA[0] += sig_e2(d_[0]); accA[1] += sig_e2(d_[1]); \
                accA[2] += sig_e2(d_[2]); accA[3] += sig_e2(d_[3]); \
                c_ = {cpB, cpB, cpB, cpB}; \
                d_ = __builtin_amdgcn_mfma_f32_16x16x32_bf16(a_, bfB, c_, 0, 0, 0); \
                accB[0] += sig_e2(d_[0]); accB[1] += sig_e2(d_[1]); \
                accB[2] += sig_e2(d_[2]); accB[3] += sig_e2(d_[3]); \
            } else { \
                const int r0_ = base_ + kg * 4; \
                f32x4 c_ = {cpA, cpA, cpA, cpA}; \
                f32x4 d_ = __builtin_amdgcn_mfma_f32_16x16x32_bf16(a_, bfA, c_, 0, 0, 0); \
                if (r0_ + 0 < P) accA[0] += sig_e2(d_[0]); \
                if (r0_ + 1 < P) accA[1] += sig_e2(d_[1]); \
                if (r0_ + 2 < P) accA[2] += sig_e2(d_[2]); \
                if (r0_ + 3 < P) accA[3] += sig_e2(d_[3]); \
                c_ = {cpB, cpB, cpB, cpB}; \
                d_ = __builtin_amdgcn_mfma_f32_16x16x32_bf16(a_, bfB, c_, 0, 0, 0); \
                if (r0_ + 0 < P) accB[0] += sig_e2(d_[0]); \
                if (r0_ + 1 < P) accB[1] += sig_e2(d_[1]); \
                if (r0_ + 2 < P) accB[2] += sig_e2(d_[2]); \
                if (r0_ + 3 < P) accB[3] += sig_e2(d_[3]); \
            } \
        } }

    #define SYNC { asm volatile("s_waitcnt lgkmcnt(0)" ::: "memory"); \
                   __builtin_amdgcn_s_barrier(); }

    if (K > 0) {
        SLOADP(0)
        SWRITEP(0)                // counted vmcnt wait (prologue, once)
        SLOADP(1)
        SYNC

        for (int p = 0; p < PH; ++p) {
            if (p + 1 < PH) SWRITEP(p + 1);   // publish next phase (pre is a phase old)
            if (p + 2 < PH) SLOADP(p + 2);    // issue loads 2 phases ahead
            CTILE(p, 0) CTILE(p, 1) CTILE(p, 2) CTILE(p, 3)
            SYNC                              // RAW barrier: vmem stays in flight
        }
    }
    #undef SLOADP
    #undef SWRITEP
    #undef CTILE
    #undef SYNC

    // Per-lane valid-row count (analytic).
    float nsum = 0.0f;
    if (K > 0) {
        int nfull = (b < Tf) ? ((Tf - 1 - b) / NB + 1) : 0;
        nsum = 4.0f * (float)nfull;
        if (Tf < T && b <= Tf && ((Tf - b) % NB) == 0) {   // block owns partial tile
            int prem = P - Tf * 16;
            int nv = prem - kg * 4; if (nv < 0) nv = 0; if (nv > 4) nv = 4;
            nsum += (float)nv;
        }
    }

    // sum(tanh) = nsum - 2*sum(sigma); fold 4 row-regs, then 4 k-groups.
    float sA = nsum - 2.0f * ((accA[0] + accA[1]) + (accA[2] + accA[3]));
    sA += __shfl_xor(sA, 16, 64);
    sA += __shfl_xor(sA, 32, 64);
    float sB = nsum - 2.0f * ((accB[0] + accB[1]) + (accB[2] + accB[3]));
    sB += __shfl_xor(sB, 16, 64);
    sB += __shfl_xor(sB, 32, 64);
    if (lane < 16) {
        wacc[g0 * 16 + lane] = sA;
        wacc[g1 * 16 + lane] = sB;
    }
    __syncthreads();
    if (tid < 128) {
        partials[(size_t)b * 128 + tid] = wacc[tid];
    }
}

// Finalize, round-9: mid-reduce fused in via VECTORIZED partials read.
// Each of 1024 threads owns 4 channels x (nblk/32) blocks as f32x4 loads:
// 512KB at 16B/lane with 4-deep ILP (~4x the in-flight bytes of the old
// scalar path that cost 6-9us from one CU).
__global__ __launch_bounds__(1024) void phot_finalize(
    const float* __restrict__ partials, int nblk, int P,
    const float* __restrict__ out_w,      // [32][128]
    const float* __restrict__ out_b,      // [32]
    const float* __restrict__ rel_bias,   // [129][2]
    const float* __restrict__ cand,       // [32]
    const float* __restrict__ norm_scale, // [1]
    const int* __restrict__ posp,         // [1]
    float* __restrict__ out)              // [32]
{
    __shared__ __align__(16) float sh[4096];   // [slice 0..31][128 ch]
    __shared__ float  cm[128];
    __shared__ float  outv[32];
    __shared__ double db[512];
    __shared__ float  bm[2];

    const int t   = threadIdx.x;
    const int chg = t & 31;         // channel group (4 channels)
    const int sl  = t >> 5;         // 0..31 slices over blocks

    const int cnt = nblk >> 5;      // nblk is a multiple of 32
    const float* p0 = partials + (size_t)(sl * cnt) * 128 + chg * 4;
    f32x4 a0 = {0,0,0,0}, a1 = {0,0,0,0}, a2 = {0,0,0,0}, a3 = {0,0,0,0};
    int i = 0;
    for (; i + 4 <= cnt; i += 4) {
        a0 += *(const f32x4*)(p0 + (size_t)(i+0) * 128);
        a1 += *(const f32x4*)(p0 + (size_t)(i+1) * 128);
        a2 += *(const f32x4*)(p0 + (size_t)(i+2) * 128);
        a3 += *(const f32x4*)(p0 + (size_t)(i+3) * 128);
    }
    for (; i < cnt; ++i) a0 += *(const f32x4*)(p0 + (size_t)i * 128);
    f32x4 acc = (a0 + a1) + (a2 + a3);
    *(f32x4*)&sh[sl * 128 + chg * 4] = acc;
    __syncthreads();

    if (t < 128) {
        float s = 0.0f;
        #pragma unroll
        for (int s2 = 0; s2 < 32; ++s2) s += sh[t + 128 * s2];
        cm[t] = s / (float)P;
    }

    // rel-bias mean, closed form per bin; idx(p)=clamp(a+p,0,128), a=pos-P+64
    if (t < 512) {
        const int c = t >> 8, j = t & 255;
        double v = 0.0;
        if (j <= 128) {
            const long long pos = (long long)(*posp);
            const long long a = pos - (long long)P + 64;
            double cnt2;
            if (j == 0) {
                long long hi = -a; if (hi > (long long)P - 1) hi = (long long)P - 1;
                cnt2 = (hi >= 0) ? (double)(hi + 1) : 0.0;
            } else if (j == 128) {
                long long lo = 128 - a; if (lo < 0) lo = 0;
                cnt2 = (lo <= (long long)P - 1) ? (double)((long long)P - lo) : 0.0;
            } else {
                long long p = (long long)j - a;
                cnt2 = (p >= 0 && p < (long long)P) ? 1.0 : 0.0;
            }
            v = cnt2 * (double)rel_bias[2*j + c];
        }
        db[t] = v;
    }
    __syncthreads();
    #pragma unroll
    for (int s = 128; s >= 1; s >>= 1) {
        if (t < 512 && (t & 255) < s) db[t] += db[t + s];
        __syncthreads();
    }
    if (t < 2) bm[t] = (float)(db[t << 8] / (double)P);
    __syncthreads();

    if (t < 32) {
        const float* wr = out_w + t * 128;
        float o0 = out_b[t], o1 = 0.f, o2 = 0.f, o3 = 0.f;
        #pragma unroll
        for (int j = 0; j < 128; j += 4) {
            o0 = fmaf(wr[j+0], cm[j+0], o0);
            o1 = fmaf(wr[j+1], cm[j+1], o1);
            o2 = fmaf(wr[j+2], cm[j+2], o2);
            o3 = fmaf(wr[j+3], cm[j+3], o3);
        }
        outv[t] = (o0+o1) + (o2+o3);
    }
    __syncthreads();

    if (t < 32) {
        float zt = tanh_fast(cand[t] + COUPLING * (outv[t] + bm[t & 1]));
        float other = __shfl_xor(zt, 1, 64);
        float m = fmaf(zt, zt, other * other);
        #pragma unroll
        for (int off = 2; off < 32; off <<= 1) m = fmaxf(m, __shfl_xor(m, off, 64));
        float scale = norm_scale[0] / sqrtf(m + EPSV);
        out[t] = (m > 0.0f) ? zt * scale : zt;
    }
}

extern "C" void kernel_launch(void* const* d_in, const int* in_sizes, int n_in,
                              void* d_out, int out_size, void* d_ws, size_t ws_size,
                              hipStream_t stream)
{
    const float* cand       = (const float*)d_in[0];
    const float* z_past     = (const float*)d_in[1];
    const float* heads_w    = (const float*)d_in[2];
    const float* heads_b    = (const float*)d_in[3];
    const float* out_w      = (const float*)d_in[4];
    const float* out_b      = (const float*)d_in[5];
    const float* rel_bias   = (const float*)d_in[6];
    const float* norm_scale = (const float*)d_in[7];
    const int*   posp       = (const int*)d_in[8];

    const int P = in_sizes[1] / 32;

    int nblk = 1024;     // 4 blocks/CU, residency guaranteed for any VGPR<=128
    size_t need = (size_t)nblk * 128 * sizeof(float);
    if (need > ws_size) {
        nblk = (int)(ws_size / (128 * sizeof(float)));
        nblk &= ~31;
        if (nblk < 32) nblk = 32;
    }
    float* partials = (float*)d_ws;

    phot_main<<<nblk, 256, 0, stream>>>(z_past, heads_w, heads_b, cand,
                                        partials, P, nblk);
    phot_finalize<<<1, 1024, 0, stream>>>(partials, nblk, P, out_w, out_b,
                                          rel_bias, cand, norm_scale, posp,
                                          (float*)d_out);
}

// Round 7
// 36.405 us; speedup vs baseline: 1.1204x; 1.0336x over previous
//
#include <hip/hip_runtime.h>
#include <hip/hip_bf16.h>
#include <math.h>

#define COUPLING 0.12f
#define EPSV 1e-8f
#define SCALE2L2E 2.8853900817779268f   // 2*log2(e): folds tanh's 2x and exp->exp2

typedef __attribute__((ext_vector_type(8))) short bf16x8;
typedef __attribute__((ext_vector_type(4))) float f32x4;

// tanh(x) from y = 2x*log2(e):  tanh = 1 - 2/(1+2^y). Inf-safe both ways.
__device__ __forceinline__ float tanh_from_e2(float y) {
    float e = __builtin_amdgcn_exp2f(y);
    float r = __builtin_amdgcn_rcpf(1.0f + e);
    return fmaf(-2.0f, r, 1.0f);
}
__device__ __forceinline__ float tanh_fast(float x) {
    return tanh_from_e2(SCALE2L2E * x);
}
// sigma(y) = 1/(1+2^y); tanh = 1 - 2*sigma. Accumulate sigma, fix up with
// valid-row count N at reduction: sum(tanh) = N - 2*sum(sigma).
__device__ __forceinline__ float sig_e2(float y) {
    float e = __builtin_amdgcn_exp2f(y);
    return __builtin_amdgcn_rcpf(1.0f + e);
}

__device__ __forceinline__ short f2bf(float f) {
    __hip_bfloat16 h = __float2bfloat16(f);
    return __builtin_bit_cast(short, h);
}

// Main, round-10. Loop body/swizzle/reduction identical to R6 (absmax 0,
// R3-R6). Two scheduling changes only:
//  - Loads issued at phase TOP, consumed (cvt+ds_write) at phase BOTTOM,
//    via two alternating NAMED pre-register sets (X/Y) and a x2-unrolled
//    phase loop (static indices, rule #20). Load age at the vmcnt wait is
//    now ~2 phases (~900-1000cy) instead of ~1 phase (~450cy) -- removes
//    the per-phase convoy stall where all 4 barrier-coupled waves sat in
//    the same vmcnt shadow (R5's depth-3 kept the consume point at the
//    phase top, which is why it was neutral).
//  - sched_barrier(0) after each SYNC (rule #18 hardening; no reorder of
//    next phase's ds_reads above the barrier).
// C/D layout: col=lane&15, row=(lane>>4)*4+reg (m89-verified).
__global__ __launch_bounds__(256, 4) void phot_main(
    const float* __restrict__ z_past,   // [P][32] fp32
    const float* __restrict__ heads_w,  // [128][64]
    const float* __restrict__ heads_b,  // [128]
    const float* __restrict__ cand,     // [32]
    float* __restrict__ partials,       // [NB][128]
    int P, int NB)                      // NB = grid size
{
    __shared__ float wacc[128];
    __shared__ float cpre_l[128];
    __shared__ __align__(16) unsigned short wbf_l[128][32];   // 8KB bf16 weights
    __shared__ __align__(16) unsigned short zb[3][4][512];    // ring: [slot][tile][16x32]

    const int tid  = threadIdx.x;
    const int lane = tid & 63;
    const int wv   = tid >> 6;
    const int col  = lane & 15;   // A-row / B-col / C-col
    const int kg   = lane >> 4;   // k-group (k = kg*8 + e)

    // ---- prep phase (block-local) ----
    if (tid < 128) {
        const float* wr = heads_w + (size_t)tid * 64;
        float s0 = heads_b[tid], s1 = 0.f, s2 = 0.f, s3 = 0.f;
        #pragma unroll
        for (int k = 0; k < 32; k += 4) {
            s0 = fmaf(wr[k+0], cand[k+0], s0);
            s1 = fmaf(wr[k+1], cand[k+1], s1);
            s2 = fmaf(wr[k+2], cand[k+2], s2);
            s3 = fmaf(wr[k+3], cand[k+3], s3);
        }
        cpre_l[tid] = SCALE2L2E * ((s0 + s1) + (s2 + s3));
        #pragma unroll
        for (int k = 0; k < 32; ++k)
            wbf_l[tid][k] = (unsigned short)f2bf(SCALE2L2E * wr[32 + k]);
    }
    __syncthreads();

    // This wave's 2 channel groups (B fragments from LDS).
    const int g0 = wv * 2, g1 = g0 + 1;
    const bf16x8 bfA = *(const bf16x8*)&wbf_l[g0 * 16 + col][kg * 8];
    const bf16x8 bfB = *(const bf16x8*)&wbf_l[g1 * 16 + col][kg * 8];
    const float  cpA = cpre_l[g0 * 16 + col];
    const float  cpB = cpre_l[g1 * 16 + col];

    f32x4 accA = {0,0,0,0}, accB = {0,0,0,0};

    const int T  = (P + 15) >> 4;             // total 16-row tiles
    const int Tf = P >> 4;                    // full tiles
    const int b  = blockIdx.x;
    const int K  = (b < T) ? ((T - 1 - b) / NB + 1) : 0;   // tiles for this block
    const int PH = (K + 3) >> 2;              // phases of 4 tiles

    // Stager lane mapping: lane covers tile floats [sr*32 + sc*8, +8).
    const int sr = lane >> 2;                 // row 0..15
    const int sc = lane & 3;                  // chunk 0..3 (8 floats = 16B bf16)
    const int woff = sr * 32 + ((sc ^ (sr & 3)) << 3);   // ushort offset in tile

    // Reader offset: row=col, chunk=kg, same XOR swizzle.
    const int roff = col * 32 + ((kg ^ (col & 3)) << 3); // ushort offset in tile

    // Two named prefetch register sets; phase q's data lives in set (q&1).
    f32x4 preA0, preB0, preA1, preB1;

    #define SLOADP(ph, S) { \
        const int j_ = 4 * (ph) + wv; \
        if (j_ < K) { \
            const int tt_ = b + j_ * NB; \
            int grow = tt_ * 16 + sr; if (grow > P - 1) grow = P - 1; \
            const float* g_ = z_past + (size_t)grow * 32 + sc * 8; \
            preA##S = *(const f32x4*)g_; \
            preB##S = *(const f32x4*)(g_ + 4); \
        } }
    #define SWRITEP(ph, S) { \
        const int j_ = 4 * (ph) + wv; \
        if (j_ < K) { \
            bf16x8 w_; \
            w_[0]=f2bf(preA##S[0]); w_[1]=f2bf(preA##S[1]); \
            w_[2]=f2bf(preA##S[2]); w_[3]=f2bf(preA##S[3]); \
            w_[4]=f2bf(preB##S[0]); w_[5]=f2bf(preB##S[1]); \
            w_[6]=f2bf(preB##S[2]); w_[7]=f2bf(preB##S[3]); \
            *(bf16x8*)(&zb[(ph) % 3][wv][woff]) = w_; \
        } }
    #define CTILE(p, j) { \
        const int jj_ = 4 * (p) + (j); \
        if (jj_ < K) { \
            const int tt_ = b + jj_ * NB; \
            const bf16x8 a_ = *(const bf16x8*)(&zb[(p) % 3][j][roff]); \
            const int base_ = tt_ * 16; \
            if (base_ + 16 <= P) { \
                f32x4 c_ = {cpA, cpA, cpA, cpA}; \
                f32x4 d_ = __builtin_amdgcn_mfma_f32_16x16x32_bf16(a_, bfA, c_, 0, 0, 0); \
                accA[0] += sig_e2(d_[0]); accA[1] += sig_e2(d_[1]); \
                accA[2] += sig_e2(d_[2]); accA[3] += sig_e2(d_[3]); \
                c_ = {cpB, cpB, cpB, cpB}; \
                d_ = __builtin_amdgcn_mfma_f32_16x16x32_bf16(a_, bfB, c_, 0, 0, 0); \
                accB[0] += sig_e2(d_[0]); accB[1] += sig_e2(d_[1]); \
                accB[2] += sig_e2(d_[2]); accB[3] += sig_e2(d_[3]); \
            } else { \
                const int r0_ = base_ + kg * 4; \
                f32x4 c_ = {cpA, cpA, cpA, cpA}; \
                f32x4 d_ = __builtin_amdgcn_mfma_f32_16x16x32_bf16(a_, bfA, c_, 0, 0, 0); \
                if (r0_ + 0 < P) accA[0] += sig_e2(d_[0]); \
                if (r0_ + 1 < P) accA[1] += sig_e2(d_[1]); \
                if (r0_ + 2 < P) accA[2] += sig_e2(d_[2]); \
                if (r0_ + 3 < P) accA[3] += sig_e2(d_[3]); \
                c_ = {cpB, cpB, cpB, cpB}; \
                d_ = __builtin_amdgcn_mfma_f32_16x16x32_bf16(a_, bfB, c_, 0, 0, 0); \
                if (r0_ + 0 < P) accB[0] += sig_e2(d_[0]); \
                if (r0_ + 1 < P) accB[1] += sig_e2(d_[1]); \
                if (r0_ + 2 < P) accB[2] += sig_e2(d_[2]); \
                if (r0_ + 3 < P) accB[3] += sig_e2(d_[3]); \
            } \
        } }

    #define SYNC { asm volatile("s_waitcnt lgkmcnt(0)" ::: "memory"); \
                   __builtin_amdgcn_s_barrier(); \
                   __builtin_amdgcn_sched_barrier(0); }

    if (K > 0) {
        // Prologue: phase-0 data -> set 0, publish; phase-1 data -> set 1.
        SLOADP(0, 0)
        SWRITEP(0, 0)             // vmcnt wait (prologue, once)
        SLOADP(1, 1)
        SYNC

        // Steady state, x2 unroll: issue loads at phase TOP, publish at
        // phase BOTTOM (load age ~2 phases at the vmcnt wait).
        for (int p = 0; p < PH; p += 2) {
            {   // even phase p: data in set 0; load p+2 -> set 0 reuse-safe
                SLOADP(p + 2, 0)
                CTILE(p, 0) CTILE(p, 1) CTILE(p, 2) CTILE(p, 3)
                SWRITEP(p + 1, 1)
                SYNC
            }
            {   // odd phase p+1 (auto-guarded if PH odd)
                SLOADP(p + 3, 1)
                CTILE(p + 1, 0) CTILE(p + 1, 1) CTILE(p + 1, 2) CTILE(p + 1, 3)
                SWRITEP(p + 2, 0)
                SYNC
            }
        }
    }
    #undef SLOADP
    #undef SWRITEP
    #undef CTILE
    #undef SYNC

    // Per-lane valid-row count (analytic).
    float nsum = 0.0f;
    if (K > 0) {
        int nfull = (b < Tf) ? ((Tf - 1 - b) / NB + 1) : 0;
        nsum = 4.0f * (float)nfull;
        if (Tf < T && b <= Tf && ((Tf - b) % NB) == 0) {   // block owns partial tile
            int prem = P - Tf * 16;
            int nv = prem - kg * 4; if (nv < 0) nv = 0; if (nv > 4) nv = 4;
            nsum += (float)nv;
        }
    }

    // sum(tanh) = nsum - 2*sum(sigma); fold 4 row-regs, then 4 k-groups.
    float sA = nsum - 2.0f * ((accA[0] + accA[1]) + (accA[2] + accA[3]));
    sA += __shfl_xor(sA, 16, 64);
    sA += __shfl_xor(sA, 32, 64);
    float sB = nsum - 2.0f * ((accB[0] + accB[1]) + (accB[2] + accB[3]));
    sB += __shfl_xor(sB, 16, 64);
    sB += __shfl_xor(sB, 32, 64);
    if (lane < 16) {
        wacc[g0 * 16 + lane] = sA;
        wacc[g1 * 16 + lane] = sB;
    }
    __syncthreads();
    if (tid < 128) {
        partials[(size_t)b * 128 + tid] = wacc[tid];
    }
}

// Finalize, round-10: the partials read crosses XCDs (written by 1024 blocks
// on 8 non-coherent L2s); latency ~700ns/round-trip dominates. R6's 4-deep
// ILP left ~8 serial round-trips (~5-7us). Now: two fully-unrolled batches
// of 16 f32x4 loads (256B/lane in flight) -> ~2 serial round-trips.
__global__ __launch_bounds__(1024) void phot_finalize(
    const float* __restrict__ partials, int nblk, int P,
    const float* __restrict__ out_w,      // [32][128]
    const float* __restrict__ out_b,      // [32]
    const float* __restrict__ rel_bias,   // [129][2]
    const float* __restrict__ cand,       // [32]
    const float* __restrict__ norm_scale, // [1]
    const int* __restrict__ posp,         // [1]
    float* __restrict__ out)              // [32]
{
    __shared__ __align__(16) float sh[4096];   // [slice 0..31][128 ch]
    __shared__ float  cm[128];
    __shared__ float  outv[32];
    __shared__ double db[512];
    __shared__ float  bm[2];

    const int t   = threadIdx.x;
    const int chg = t & 31;         // channel group (4 channels)
    const int sl  = t >> 5;         // 0..31 slices over blocks

    const int cnt = nblk >> 5;      // nblk is a multiple of 32
    const float* p0 = partials + (size_t)(sl * cnt) * 128 + chg * 4;
    f32x4 acc = {0,0,0,0};
    if (cnt == 32) {
        f32x4 v[16];
        #pragma unroll
        for (int i = 0; i < 16; ++i) v[i] = *(const f32x4*)(p0 + (size_t)i * 128);
        f32x4 s0 = {0,0,0,0}, s1 = {0,0,0,0}, s2 = {0,0,0,0}, s3 = {0,0,0,0};
        #pragma unroll
        for (int i = 0; i < 16; i += 4) {
            s0 += v[i+0]; s1 += v[i+1]; s2 += v[i+2]; s3 += v[i+3];
        }
        #pragma unroll
        for (int i = 0; i < 16; ++i) v[i] = *(const f32x4*)(p0 + (size_t)(16 + i) * 128);
        #pragma unroll
        for (int i = 0; i < 16; i += 4) {
            s0 += v[i+0]; s1 += v[i+1]; s2 += v[i+2]; s3 += v[i+3];
        }
        acc = (s0 + s1) + (s2 + s3);
    } else {
        f32x4 a0 = {0,0,0,0}, a1 = {0,0,0,0}, a2 = {0,0,0,0}, a3 = {0,0,0,0};
        int i = 0;
        for (; i + 4 <= cnt; i += 4) {
            a0 += *(const f32x4*)(p0 + (size_t)(i+0) * 128);
            a1 += *(const f32x4*)(p0 + (size_t)(i+1) * 128);
            a2 += *(const f32x4*)(p0 + (size_t)(i+2) * 128);
            a3 += *(const f32x4*)(p0 + (size_t)(i+3) * 128);
        }
        for (; i < cnt; ++i) a0 += *(const f32x4*)(p0 + (size_t)i * 128);
        acc = (a0 + a1) + (a2 + a3);
    }
    *(f32x4*)&sh[sl * 128 + chg * 4] = acc;
    __syncthreads();

    if (t < 128) {
        float s = 0.0f;
        #pragma unroll
        for (int s2 = 0; s2 < 32; ++s2) s += sh[t + 128 * s2];
        cm[t] = s / (float)P;
    }

    // rel-bias mean, closed form per bin; idx(p)=clamp(a+p,0,128), a=pos-P+64
    if (t < 512) {
        const int c = t >> 8, j = t & 255;
        double v = 0.0;
        if (j <= 128) {
            const long long pos = (long long)(*posp);
            const long long a = pos - (long long)P + 64;
            double cnt2;
            if (j == 0) {
                long long hi = -a; if (hi > (long long)P - 1) hi = (long long)P - 1;
                cnt2 = (hi >= 0) ? (double)(hi + 1) : 0.0;
            } else if (j == 128) {
                long long lo = 128 - a; if (lo < 0) lo = 0;
                cnt2 = (lo <= (long long)P - 1) ? (double)((long long)P - lo) : 0.0;
            } else {
                long long p = (long long)j - a;
                cnt2 = (p >= 0 && p < (long long)P) ? 1.0 : 0.0;
            }
            v = cnt2 * (double)rel_bias[2*j + c];
        }
        db[t] = v;
    }
    __syncthreads();
    #pragma unroll
    for (int s = 128; s >= 1; s >>= 1) {
        if (t < 512 && (t & 255) < s) db[t] += db[t + s];
        __syncthreads();
    }
    if (t < 2) bm[t] = (float)(db[t << 8] / (double)P);
    __syncthreads();

    if (t < 32) {
        const float* wr = out_w + t * 128;
        float o0 = out_b[t], o1 = 0.f, o2 = 0.f, o3 = 0.f;
        #pragma unroll
        for (int j = 0; j < 128; j += 4) {
            o0 = fmaf(wr[j+0], cm[j+0], o0);
            o1 = fmaf(wr[j+1], cm[j+1], o1);
            o2 = fmaf(wr[j+2], cm[j+2], o2);
            o3 = fmaf(wr[j+3], cm[j+3], o3);
        }
        outv[t] = (o0+o1) + (o2+o3);
    }
    __syncthreads();

    if (t < 32) {
        float zt = tanh_fast(cand[t] + COUPLING * (outv[t] + bm[t & 1]));
        float other = __shfl_xor(zt, 1, 64);
        float m = fmaf(zt, zt, other * other);
        #pragma unroll
        for (int off = 2; off < 32; off <<= 1) m = fmaxf(m, __shfl_xor(m, off, 64));
        float scale = norm_scale[0] / sqrtf(m + EPSV);
        out[t] = (m > 0.0f) ? zt * scale : zt;
    }
}

extern "C" void kernel_launch(void* const* d_in, const int* in_sizes, int n_in,
                              void* d_out, int out_size, void* d_ws, size_t ws_size,
                              hipStream_t stream)
{
    const float* cand       = (const float*)d_in[0];
    const float* z_past     = (const float*)d_in[1];
    const float* heads_w    = (const float*)d_in[2];
    const float* heads_b    = (const float*)d_in[3];
    const float* out_w      = (const float*)d_in[4];
    const float* out_b      = (const float*)d_in[5];
    const float* rel_bias   = (const float*)d_in[6];
    const float* norm_scale = (const float*)d_in[7];
    const int*   posp       = (const int*)d_in[8];

    const int P = in_sizes[1] / 32;

    int nblk = 1024;     // 4 blocks/CU, residency guaranteed for any VGPR<=128
    size_t need = (size_t)nblk * 128 * sizeof(float);
    if (need > ws_size) {
        nblk = (int)(ws_size / (128 * sizeof(float)));
        nblk &= ~31;
        if (nblk < 32) nblk = 32;
    }
    float* partials = (float*)d_ws;

    phot_main<<<nblk, 256, 0, stream>>>(z_past, heads_w, heads_b, cand,
                                        partials, P, nblk);
    phot_finalize<<<1, 1024, 0, stream>>>(partials, nblk, P, out_w, out_b,
                                          rel_bias, cand, norm_scale, posp,
                                          (float*)d_out);
}